// Round 4
// baseline (121.344 us; speedup 1.0000x reference)
//
#include <hip/hip_runtime.h>
#include <hip/hip_bf16.h>

#define DEPTH 64
#define NH 8
#define SEQL 512
#define BATCH 4
#define FFDIM 128
#define PROJ (DEPTH*NH)   // 512
#define LOG2E 1.44269504088896340736f

typedef __hip_bfloat16 bf16;
typedef __attribute__((ext_vector_type(8))) short short8;
typedef __attribute__((ext_vector_type(4))) float floatx4;

__device__ __forceinline__ short f2bs(float f) {
    __hip_bfloat16 h = __float2bfloat16(f);
    return *reinterpret_cast<short*>(&h);
}
__device__ __forceinline__ float bs2f(short s) {
    __hip_bfloat16 h = *reinterpret_cast<__hip_bfloat16*>(&s);
    return __bfloat162float(h);
}

// ---------------- K1: fused front = qkv (384 blocks) + pbias (16384 blocks) ----------------
// qkv: q,k -> [B,h,S,d]; v -> vT[B,h,d,S].  pbias: p[b,h,i,j] (bf16).
__global__ __launch_bounds__(256) void front_kernel(
    const float* __restrict__ seq, const float* __restrict__ Wq,
    const float* __restrict__ Wk, const float* __restrict__ Wv,
    const float* __restrict__ pos, const float* __restrict__ Wp,
    const float* __restrict__ bp,
    bf16* __restrict__ q, bf16* __restrict__ k, bf16* __restrict__ vT,
    bf16* __restrict__ p)
{
    __shared__ __align__(16) union {
        struct { short sS[64][72]; short sW[128][72]; } g;   // 27648 B (sT aliases sW)
        struct { float sW2[4][132]; float sb[8]; } pb;
    } U;
    int t = threadIdx.x;
    int bid = blockIdx.x;

    if (bid < 384) {
        // ---------------- qkv role ----------------
        int lane = t & 63, w = t >> 6;
        int z = bid >> 7, rem = bid & 127;
        int mi = rem & 31, ni = rem >> 5;
        const float* W; int vflag = 0; bf16* out;
        if (z == 0)      { W = Wq; out = q; }
        else if (z == 1) { W = Wk; out = k; }
        else             { W = Wv; out = vT; vflag = 1; }
        int m0 = mi * 64;
        int n0 = ni * 128;

        for (int idx = t; idx < 4096; idx += 256) {
            int r = idx >> 6, kk = idx & 63;
            U.g.sS[r][kk] = f2bs(seq[(long)(m0 + r)*64 + kk]);
        }
        for (int idx = t; idx < 8192; idx += 256) {
            int kk = idx >> 7, n = idx & 127;
            U.g.sW[n][kk] = f2bs(W[kk*512 + n0 + n]);
        }
        __syncthreads();

        int ln = lane & 15, g4 = lane >> 4;
        int mt = w;
        floatx4 acc[2][4];
        #pragma unroll
        for (int nh = 0; nh < 2; nh++)
            #pragma unroll
            for (int nt = 0; nt < 4; nt++) acc[nh][nt] = (floatx4){0.f,0.f,0.f,0.f};
        #pragma unroll
        for (int ks = 0; ks < 2; ks++) {
            short8 af = *(const short8*)&U.g.sS[mt*16 + ln][ks*32 + g4*8];
            #pragma unroll
            for (int nh = 0; nh < 2; nh++)
                #pragma unroll
                for (int nt = 0; nt < 4; nt++) {
                    short8 bfv = *(const short8*)&U.g.sW[nh*64 + nt*16 + ln][ks*32 + g4*8];
                    acc[nh][nt] = __builtin_amdgcn_mfma_f32_16x16x32_bf16(af, bfv, acc[nh][nt], 0, 0, 0);
                }
        }

        if (!vflag) {
            #pragma unroll
            for (int nh = 0; nh < 2; nh++)
                #pragma unroll
                for (int nt = 0; nt < 4; nt++)
                    #pragma unroll
                    for (int r = 0; r < 4; r++) {
                        int grow = m0 + mt*16 + g4*4 + r;
                        int col  = n0 + nh*64 + nt*16 + ln;
                        int b = grow >> 9, s = grow & 511;
                        int h = col >> 6, d = col & 63;
                        out[(((long)(b*8 + h)*512) + s)*64 + d] = __float2bfloat16(acc[nh][nt][r]);
                    }
        } else {
            __syncthreads();                      // sW reads done; reuse as sT
            short (*sT)[72] = U.g.sW;
            #pragma unroll
            for (int nh = 0; nh < 2; nh++)
                #pragma unroll
                for (int nt = 0; nt < 4; nt++)
                    #pragma unroll
                    for (int r = 0; r < 4; r++)
                        sT[nh*64 + nt*16 + ln][mt*16 + g4*4 + r] = f2bs(acc[nh][nt][r]);
            __syncthreads();
            int b = m0 >> 9, s0 = m0 & 511;
            for (int idx = t; idx < 1024; idx += 256) {
                int lc = idx >> 3, c8 = idx & 7;
                *(uint4*)(out + ((long)(b*512 + n0 + lc))*512 + s0 + c8*8) =
                    *(const uint4*)&sT[lc][c8*8];
            }
        }
    } else {
        // ---------------- pbias role ----------------
        int pid = bid - 384;
        for (int i = t; i < 512; i += 256) {
            int sub = i >> 7, rest = i & 127;
            int lk = rest >> 3, h = rest & 7;
            int kk = ((lk >> 2) << 4) + sub*4 + (lk & 3);
            U.pb.sW2[sub][lk*8 + h] = Wp[kk*8 + h];
        }
        if (t < 8) U.pb.sb[t] = bp[t];
        __syncthreads();

        int sub = t & 3;
        int lrow = t >> 2;
        long row = (long)pid*64 + lrow;

        const float4* src = (const float4*)(pos + row*64);
        float4 ch[4];
        #pragma unroll
        for (int i = 0; i < 4; i++) ch[i] = src[i*4 + sub];

        float acc[8];
        #pragma unroll
        for (int h = 0; h < 8; h++) acc[h] = 0.f;
        #pragma unroll
        for (int i = 0; i < 4; i++) {
            #pragma unroll
            for (int e = 0; e < 4; e++) {
                float x = ((const float*)&ch[i])[e];
                int lk = i*4 + e;
                const float4* wr = (const float4*)&U.pb.sW2[sub][lk*8];
                float4 wa = wr[0], wb = wr[1];
                acc[0] += x*wa.x; acc[1] += x*wa.y; acc[2] += x*wa.z; acc[3] += x*wa.w;
                acc[4] += x*wb.x; acc[5] += x*wb.y; acc[6] += x*wb.z; acc[7] += x*wb.w;
            }
        }
        #pragma unroll
        for (int h = 0; h < 8; h++) {
            acc[h] += __shfl_xor(acc[h], 1, 64);
            acc[h] += __shfl_xor(acc[h], 2, 64);
        }
        int b = (int)(row >> 18);
        int rem = (int)(row & 262143);
        int i = rem >> 9, j = rem & 511;
        int h1 = sub, h2 = sub + 4;
        p[(((long)(b*8 + h1)*512 + i) << 9) + j] = __float2bfloat16(acc[h1] + U.pb.sb[h1]);
        p[(((long)(b*8 + h2)*512 + i) << 9) + j] = __float2bfloat16(acc[h2] + U.pb.sb[h2]);
    }
}

// ---------------- K2: flash attention, 32-row tiles, 2 waves, p-prefetch ----------------
// grid = 4*8*16 = 512 blocks x 128 thr (2 waves). Fixed-max softmax (scores bounded).
__global__ __launch_bounds__(128) void attn_kernel(
    const bf16* __restrict__ q, const bf16* __restrict__ k,
    const bf16* __restrict__ vT, const bf16* __restrict__ p,
    bf16* __restrict__ heads)
{
    __shared__ __align__(16) short sQ[32*72];
    __shared__ __align__(16) short sK[64*72];
    __shared__ __align__(16) short sV[64*72];      // [d][j]
    __shared__ __align__(16) short sP[2][16*72];

    int t = threadIdx.x;
    int lane = t & 63, w = t >> 6;
    int bid = blockIdx.x;
    int it = bid & 15;
    int bh = bid >> 4;
    int i0 = it*32;

    const bf16* qb = q + ((long)bh*SEQL + i0)*DEPTH;
    const bf16* kb = k + (long)bh*SEQL*DEPTH;
    const bf16* vb = vT + (long)bh*DEPTH*SEQL;     // [d][s]
    const bf16* pb = p + ((long)bh*SEQL + i0)*SEQL;

    for (int c = t; c < 256; c += 128) {
        int r = c >> 3, c8 = c & 7;
        *(uint4*)((char*)sQ + r*144 + c8*16) = *(const uint4*)(qb + r*64 + c8*8);
    }

    int ln = lane & 15, g4 = lane >> 4;
    float lsum[4];
    floatx4 oacc[4];
    #pragma unroll
    for (int r = 0; r < 4; r++) lsum[r] = 0.f;
    #pragma unroll
    for (int ds = 0; ds < 4; ds++) oacc[ds] = (floatx4){0.f,0.f,0.f,0.f};

    // prefetch p for jt=0
    unsigned short pf[16];
    #pragma unroll
    for (int js = 0; js < 4; js++)
        #pragma unroll
        for (int r = 0; r < 4; r++)
            pf[js*4 + r] = *(const unsigned short*)&pb[(long)(w*16 + g4*4 + r)*SEQL + js*16 + ln];

    #pragma unroll
    for (int jt = 0; jt < 8; jt++) {
        __syncthreads();
        int j0 = jt*64;
        for (int c = t; c < 512; c += 128) {        // K tile [j][d]
            int r = c >> 3, c8 = c & 7;
            *(uint4*)((char*)sK + r*144 + c8*16) = *(const uint4*)(kb + (long)(j0 + r)*64 + c8*8);
        }
        for (int c = t; c < 512; c += 128) {        // V tile [d][j] from vT
            int r = c >> 3, c8 = c & 7;
            *(uint4*)((char*)sV + r*144 + c8*16) = *(const uint4*)(vb + (long)r*512 + j0 + c8*8);
        }
        __syncthreads();

        // consume current p, prefetch next tile's p
        unsigned short cur[16];
        #pragma unroll
        for (int e = 0; e < 16; e++) cur[e] = pf[e];
        if (jt < 7) {
            int jn = (jt + 1)*64;
            #pragma unroll
            for (int js = 0; js < 4; js++)
                #pragma unroll
                for (int r = 0; r < 4; r++)
                    pf[js*4 + r] = *(const unsigned short*)&pb[(long)(w*16 + g4*4 + r)*SEQL + jn + js*16 + ln];
        }

        floatx4 sacc[4];
        #pragma unroll
        for (int js = 0; js < 4; js++) sacc[js] = (floatx4){0.f,0.f,0.f,0.f};
        #pragma unroll
        for (int kk = 0; kk < 2; kk++) {
            short8 aq = *(const short8*)((const char*)sQ + (w*16 + ln)*144 + kk*64 + g4*16);
            #pragma unroll
            for (int js = 0; js < 4; js++) {
                short8 bk = *(const short8*)((const char*)sK + (js*16 + ln)*144 + kk*64 + g4*16);
                sacc[js] = __builtin_amdgcn_mfma_f32_16x16x32_bf16(aq, bk, sacc[js], 0, 0, 0);
            }
        }
        // P = exp(S/8 + p); accumulate per-lane row sums
        #pragma unroll
        for (int js = 0; js < 4; js++)
            #pragma unroll
            for (int r = 0; r < 4; r++) {
                float pv = bs2f((short)cur[js*4 + r]);
                float e = exp2f((sacc[js][r]*0.125f + pv)*LOG2E);
                lsum[r] += e;
                sP[w][(g4*4 + r)*72 + js*16 + ln] = f2bs(e);
            }
        // O += P @ V
        #pragma unroll
        for (int kk = 0; kk < 2; kk++) {
            short8 ap = *(const short8*)((const char*)sP[w] + ln*144 + kk*64 + g4*16);
            #pragma unroll
            for (int ds = 0; ds < 4; ds++) {
                short8 bv = *(const short8*)((const char*)sV + (ds*16 + ln)*144 + kk*64 + g4*16);
                oacc[ds] = __builtin_amdgcn_mfma_f32_16x16x32_bf16(ap, bv, oacc[ds], 0, 0, 0);
            }
        }
    }

    #pragma unroll
    for (int r = 0; r < 4; r++)
        #pragma unroll
        for (int m = 1; m < 16; m <<= 1) lsum[r] += __shfl_xor(lsum[r], m, 64);

    int b = bh >> 3, h = bh & 7;
    #pragma unroll
    for (int ds = 0; ds < 4; ds++)
        #pragma unroll
        for (int r = 0; r < 4; r++) {
            float val = oacc[ds][r] / lsum[r];
            int gi = i0 + w*16 + g4*4 + r;
            int col = h*64 + ds*16 + ln;
            heads[((long)b*SEQL + gi)*PROJ + col] = __float2bfloat16(val);
        }
}

// ---------------- K3: fused tail: o-proj + LN + FFN + LN ----------------
// 256 blocks x 256 thr (4 waves); 8 rows/block, 2 rows/wave; vector LDS reads.
__global__ __launch_bounds__(256) void tail_kernel(
    const bf16* __restrict__ heads, const float* __restrict__ Wo,
    const float* __restrict__ seq, const float* __restrict__ g_att,
    const float* __restrict__ b_att, const float* __restrict__ W1,
    const float* __restrict__ b1, const float* __restrict__ W2,
    const float* __restrict__ b2, const float* __restrict__ g_ff,
    const float* __restrict__ b_ff, float* __restrict__ out)
{
    __shared__ __align__(16) short sH[8][520];
    __shared__ float sX[8][68];
    __shared__ float sHid[8][132];
    int t = threadIdx.x;
    int w = t >> 6, lane = t & 63;
    long g0 = (long)blockIdx.x*8;

    for (int idx = t; idx < 512; idx += 256) {
        int r = idx >> 6, c8 = idx & 63;
        *(uint4*)((char*)&sH[r][0] + c8*16) = *(const uint4*)(heads + (g0 + r)*PROJ + c8*8);
    }
    __syncthreads();

    int r0 = w*2, r1 = w*2 + 1;
    float acc0 = 0.f, acc1 = 0.f;
    #pragma unroll 4
    for (int kk8 = 0; kk8 < 64; kk8++) {
        short8 a0 = *(const short8*)&sH[r0][kk8*8];
        short8 a1 = *(const short8*)&sH[r1][kk8*8];
        #pragma unroll
        for (int e = 0; e < 8; e++) {
            float wv = Wo[(kk8*8 + e)*DEPTH + lane];
            acc0 += bs2f(a0[e])*wv;
            acc1 += bs2f(a1[e])*wv;
        }
    }
    float ga = g_att[lane], ba = b_att[lane];
    float xn[2];
    #pragma unroll
    for (int rr = 0; rr < 2; rr++) {
        long row = g0 + w*2 + rr;
        float x0 = (rr ? acc1 : acc0) + seq[row*DEPTH + lane];
        float s1 = x0, s2 = x0*x0;
        #pragma unroll
        for (int m = 1; m < 64; m <<= 1) { s1 += __shfl_xor(s1, m, 64); s2 += __shfl_xor(s2, m, 64); }
        float mu = s1*(1.f/64.f);
        float var = s2*(1.f/64.f) - mu*mu;
        float rstd = rsqrtf(var + 1e-5f);
        xn[rr] = (x0 - mu)*rstd*ga + ba;
        sX[w*2 + rr][lane] = xn[rr];
    }

    float b1a = b1[lane], b1b = b1[lane + 64];
    float h00 = b1a, h01 = b1b, h10 = b1a, h11 = b1b;
    #pragma unroll 4
    for (int kk = 0; kk < DEPTH; kk++) {
        float w0 = W1[kk*FFDIM + lane];
        float w1 = W1[kk*FFDIM + 64 + lane];
        float x0v = sX[r0][kk], x1v = sX[r1][kk];
        h00 += x0v*w0; h01 += x0v*w1;
        h10 += x1v*w0; h11 += x1v*w1;
    }
    sHid[r0][lane] = fmaxf(h00, 0.f); sHid[r0][lane + 64] = fmaxf(h01, 0.f);
    sHid[r1][lane] = fmaxf(h10, 0.f); sHid[r1][lane + 64] = fmaxf(h11, 0.f);

    float bb = b2[lane];
    float acc20 = bb, acc21 = bb;
    #pragma unroll 4
    for (int kk = 0; kk < FFDIM; kk++) {
        float wv = W2[kk*DEPTH + lane];
        acc20 += sHid[r0][kk]*wv;
        acc21 += sHid[r1][kk]*wv;
    }
    float gf = g_ff[lane], bf = b_ff[lane];
    #pragma unroll
    for (int rr = 0; rr < 2; rr++) {
        long row = g0 + w*2 + rr;
        float z = xn[rr] + (rr ? acc21 : acc20);
        float t1 = z, t2 = z*z;
        #pragma unroll
        for (int m = 1; m < 64; m <<= 1) { t1 += __shfl_xor(t1, m, 64); t2 += __shfl_xor(t2, m, 64); }
        float mu2 = t1*(1.f/64.f);
        float var2 = t2*(1.f/64.f) - mu2*mu2;
        float rstd2 = rsqrtf(var2 + 1e-5f);
        out[row*DEPTH + lane] = (z - mu2)*rstd2*gf + bf;
    }
}

extern "C" void kernel_launch(void* const* d_in, const int* in_sizes, int n_in,
                              void* d_out, int out_size, void* d_ws, size_t ws_size,
                              hipStream_t stream) {
    const float* seq   = (const float*)d_in[0];
    const float* pos   = (const float*)d_in[1];
    const float* Wq    = (const float*)d_in[2];
    const float* Wk    = (const float*)d_in[3];
    const float* Wv    = (const float*)d_in[4];
    const float* Wo    = (const float*)d_in[5];
    const float* Wp    = (const float*)d_in[6];
    const float* bp    = (const float*)d_in[7];
    const float* W1    = (const float*)d_in[8];
    const float* b1    = (const float*)d_in[9];
    const float* W2    = (const float*)d_in[10];
    const float* b2    = (const float*)d_in[11];
    const float* g_att = (const float*)d_in[12];
    const float* b_att = (const float*)d_in[13];
    const float* g_ff  = (const float*)d_in[14];
    const float* b_ff  = (const float*)d_in[15];
    float* outp = (float*)d_out;

    bf16* qb  = (bf16*)d_ws;
    bf16* kb  = qb + 1048576;
    bf16* vTb = kb + 1048576;      // [B,h,d,S]
    bf16* pb  = vTb + 1048576;
    bf16* hb  = pb + 8388608;

    front_kernel<<<16768, 256, 0, stream>>>(seq, Wq, Wk, Wv, pos, Wp, bp,
                                            qb, kb, vTb, pb);
    attn_kernel <<<512,   128, 0, stream>>>(qb, kb, vTb, pb, hb);
    tail_kernel <<<256,   256, 0, stream>>>(hb, Wo, seq, g_att, b_att,
                                            W1, b1, W2, b2, g_ff, b_ff, outp);
}

// Round 5
// 113.600 us; speedup vs baseline: 1.0682x; 1.0682x over previous
//
#include <hip/hip_runtime.h>
#include <hip/hip_bf16.h>

#define DEPTH 64
#define NH 8
#define SEQL 512
#define BATCH 4
#define FFDIM 128
#define PROJ (DEPTH*NH)   // 512
#define LOG2E 1.44269504088896340736f

typedef __hip_bfloat16 bf16;
typedef __attribute__((ext_vector_type(8))) short short8;
typedef __attribute__((ext_vector_type(4))) float floatx4;

__device__ __forceinline__ short f2bs(float f) {
    __hip_bfloat16 h = __float2bfloat16(f);
    return *reinterpret_cast<short*>(&h);
}
__device__ __forceinline__ float bs2f(short s) {
    __hip_bfloat16 h = *reinterpret_cast<__hip_bfloat16*>(&s);
    return __bfloat162float(h);
}

// ---------------- K1: QKV projection via MFMA, fp32 -> bf16 ----------------
// q,k -> [B,h,S,d]; v -> vT[B,h,d,S].
__global__ __launch_bounds__(256) void qkv_kernel(
    const float* __restrict__ seq, const float* __restrict__ Wq,
    const float* __restrict__ Wk, const float* __restrict__ Wv,
    bf16* __restrict__ q, bf16* __restrict__ k, bf16* __restrict__ vT)
{
    __shared__ __align__(16) short sS[64][72];
    __shared__ __align__(16) short sW[128][72];
    __shared__ __align__(16) short sT[128][72];
    int t = threadIdx.x;
    int lane = t & 63, w = t >> 6;
    const float* W; int vflag = 0;
    bf16* out;
    if (blockIdx.z == 0)      { W = Wq; out = q; }
    else if (blockIdx.z == 1) { W = Wk; out = k; }
    else                      { W = Wv; out = vT; vflag = 1; }
    int m0 = blockIdx.x * 64;
    int n0 = blockIdx.y * 128;

    for (int idx = t; idx < 4096; idx += 256) {
        int r = idx >> 6, kk = idx & 63;
        sS[r][kk] = f2bs(seq[(long)(m0 + r)*64 + kk]);
    }
    for (int idx = t; idx < 8192; idx += 256) {
        int kk = idx >> 7, n = idx & 127;
        sW[n][kk] = f2bs(W[kk*512 + n0 + n]);
    }
    __syncthreads();

    int ln = lane & 15, g4 = lane >> 4;
    int mt = w;
    floatx4 acc[2][4];
    #pragma unroll
    for (int nh = 0; nh < 2; nh++)
        #pragma unroll
        for (int nt = 0; nt < 4; nt++) acc[nh][nt] = (floatx4){0.f,0.f,0.f,0.f};
    #pragma unroll
    for (int ks = 0; ks < 2; ks++) {
        short8 af = *(const short8*)&sS[mt*16 + ln][ks*32 + g4*8];
        #pragma unroll
        for (int nh = 0; nh < 2; nh++)
            #pragma unroll
            for (int nt = 0; nt < 4; nt++) {
                short8 bfv = *(const short8*)&sW[nh*64 + nt*16 + ln][ks*32 + g4*8];
                acc[nh][nt] = __builtin_amdgcn_mfma_f32_16x16x32_bf16(af, bfv, acc[nh][nt], 0, 0, 0);
            }
    }

    if (!vflag) {
        #pragma unroll
        for (int nh = 0; nh < 2; nh++)
            #pragma unroll
            for (int nt = 0; nt < 4; nt++)
                #pragma unroll
                for (int r = 0; r < 4; r++) {
                    int grow = m0 + mt*16 + g4*4 + r;
                    int col  = n0 + nh*64 + nt*16 + ln;
                    int b = grow >> 9, s = grow & 511;
                    int h = col >> 6, d = col & 63;
                    out[(((long)(b*8 + h)*512) + s)*64 + d] = __float2bfloat16(acc[nh][nt][r]);
                }
    } else {
        #pragma unroll
        for (int nh = 0; nh < 2; nh++)
            #pragma unroll
            for (int nt = 0; nt < 4; nt++)
                #pragma unroll
                for (int r = 0; r < 4; r++)
                    sT[nh*64 + nt*16 + ln][mt*16 + g4*4 + r] = f2bs(acc[nh][nt][r]);
        __syncthreads();
        int b = m0 >> 9, s0 = m0 & 511;
        for (int idx = t; idx < 1024; idx += 256) {
            int lc = idx >> 3, c8 = idx & 7;
            *(uint4*)(out + ((long)(b*512 + n0 + lc))*512 + s0 + c8*8) =
                *(const uint4*)&sT[lc][c8*8];
        }
    }
}

// ---------------- K2: positional bias, 2 rows/thread for MLP ----------------
// p stored [b,i,j,h] (8 bf16 = 16B per (i,j)); one 16B store per row by sub==0.
// 8192 blocks x 256 thr; __launch_bounds__(256,8) pins 32 waves/CU.
__global__ __launch_bounds__(256, 8) void pbias_kernel(
    const float* __restrict__ pos, const float* __restrict__ Wp,
    const float* __restrict__ bp, bf16* __restrict__ p)
{
    __shared__ __align__(16) float sW2[4][132];
    __shared__ float sb[8];
    int t = threadIdx.x;
    for (int i = t; i < 512; i += 256) {
        int sub = i >> 7, rest = i & 127;
        int lk = rest >> 3, h = rest & 7;
        int kk = ((lk >> 2) << 4) + sub*4 + (lk & 3);
        sW2[sub][lk*8 + h] = Wp[kk*8 + h];
    }
    if (t < 8) sb[t] = bp[t];
    __syncthreads();

    int sub = t & 3;
    int lr = t >> 2;                            // 0..63
    long rowA = (long)blockIdx.x*128 + lr;
    long rowB = rowA + 64;

    const float4* srcA = (const float4*)(pos + rowA*64);
    const float4* srcB = (const float4*)(pos + rowB*64);
    float4 chA[4], chB[4];
    #pragma unroll
    for (int i = 0; i < 4; i++) chA[i] = srcA[i*4 + sub];
    #pragma unroll
    for (int i = 0; i < 4; i++) chB[i] = srcB[i*4 + sub];

    float accA[8], accB[8];
    #pragma unroll
    for (int h = 0; h < 8; h++) { accA[h] = 0.f; accB[h] = 0.f; }
    #pragma unroll
    for (int i = 0; i < 4; i++) {
        #pragma unroll
        for (int e = 0; e < 4; e++) {
            int lk = i*4 + e;
            const float4* wr = (const float4*)&sW2[sub][lk*8];
            float4 wa = wr[0], wb = wr[1];
            float xA = ((const float*)&chA[i])[e];
            float xB = ((const float*)&chB[i])[e];
            accA[0] += xA*wa.x; accA[1] += xA*wa.y; accA[2] += xA*wa.z; accA[3] += xA*wa.w;
            accA[4] += xA*wb.x; accA[5] += xA*wb.y; accA[6] += xA*wb.z; accA[7] += xA*wb.w;
            accB[0] += xB*wa.x; accB[1] += xB*wa.y; accB[2] += xB*wa.z; accB[3] += xB*wa.w;
            accB[4] += xB*wb.x; accB[5] += xB*wb.y; accB[6] += xB*wb.z; accB[7] += xB*wb.w;
        }
    }
    #pragma unroll
    for (int h = 0; h < 8; h++) {
        accA[h] += __shfl_xor(accA[h], 1, 64);
        accA[h] += __shfl_xor(accA[h], 2, 64);
        accB[h] += __shfl_xor(accB[h], 1, 64);
        accB[h] += __shfl_xor(accB[h], 2, 64);
    }
    if (sub == 0) {
        short8 vA, vB;
        #pragma unroll
        for (int h = 0; h < 8; h++) {
            vA[h] = f2bs(accA[h] + sb[h]);
            vB[h] = f2bs(accB[h] + sb[h]);
        }
        *(short8*)(p + rowA*8) = vA;
        *(short8*)(p + rowB*8) = vB;
    }
}

// ---------------- K3: flash attention, fixed-max softmax, p-prefetch ----------------
// grid = 4*8*8 = 256 blocks x 256 thr (4 waves), 64-row i-tiles.
__global__ __launch_bounds__(256) void attn_kernel(
    const bf16* __restrict__ q, const bf16* __restrict__ k,
    const bf16* __restrict__ vT, const bf16* __restrict__ p,
    bf16* __restrict__ heads)
{
    __shared__ __align__(16) short sQ[64*72];
    __shared__ __align__(16) short sK[64*72];
    __shared__ __align__(16) short sV[64*72];      // [d][j]
    __shared__ __align__(16) short sP[4][16*72];

    int t = threadIdx.x;
    int lane = t & 63, w = t >> 6;
    int bid = blockIdx.x;
    int it = bid & 7;
    int bh = bid >> 3;
    int i0 = it*64;
    int b = bh >> 3, h = bh & 7;

    const bf16* qb = q + ((long)bh*SEQL + i0)*DEPTH;
    const bf16* kb = k + (long)bh*SEQL*DEPTH;
    const bf16* vb = vT + (long)bh*DEPTH*SEQL;     // [d][s]
    // p layout [b,i,j,h]: element (gi,gj) at pb[(gi*512+gj)*8]
    const bf16* pb = p + (((long)b*512 + i0)*512)*8 + h;

    for (int c = t; c < 512; c += 256) {
        int r = c >> 3, c8 = c & 7;
        *(uint4*)((char*)sQ + r*144 + c8*16) = *(const uint4*)(qb + r*64 + c8*8);
    }

    int ln = lane & 15, g4 = lane >> 4;
    float lsum[4];
    floatx4 oacc[4];
    #pragma unroll
    for (int r = 0; r < 4; r++) lsum[r] = 0.f;
    #pragma unroll
    for (int ds = 0; ds < 4; ds++) oacc[ds] = (floatx4){0.f,0.f,0.f,0.f};

    // prefetch p for jt=0
    unsigned short pf[16];
    #pragma unroll
    for (int js = 0; js < 4; js++)
        #pragma unroll
        for (int r = 0; r < 4; r++)
            pf[js*4 + r] = *(const unsigned short*)&pb[((long)(w*16 + g4*4 + r)*512 + js*16 + ln)*8];

    for (int jt = 0; jt < 8; jt++) {
        __syncthreads();
        int j0 = jt*64;
        for (int c = t; c < 512; c += 256) {        // K tile [j][d]
            int r = c >> 3, c8 = c & 7;
            *(uint4*)((char*)sK + r*144 + c8*16) = *(const uint4*)(kb + (long)(j0 + r)*64 + c8*8);
        }
        for (int c = t; c < 512; c += 256) {        // V tile [d][j] from vT
            int r = c >> 3, c8 = c & 7;
            *(uint4*)((char*)sV + r*144 + c8*16) = *(const uint4*)(vb + (long)r*512 + j0 + c8*8);
        }
        __syncthreads();

        unsigned short cur[16];
        #pragma unroll
        for (int e = 0; e < 16; e++) cur[e] = pf[e];
        if (jt < 7) {
            int jn = (jt + 1)*64;
            #pragma unroll
            for (int js = 0; js < 4; js++)
                #pragma unroll
                for (int r = 0; r < 4; r++)
                    pf[js*4 + r] = *(const unsigned short*)&pb[((long)(w*16 + g4*4 + r)*512 + jn + js*16 + ln)*8];
        }

        floatx4 sacc[4];
        #pragma unroll
        for (int js = 0; js < 4; js++) sacc[js] = (floatx4){0.f,0.f,0.f,0.f};
        #pragma unroll
        for (int kk = 0; kk < 2; kk++) {
            short8 aq = *(const short8*)((const char*)sQ + (w*16 + ln)*144 + kk*64 + g4*16);
            #pragma unroll
            for (int js = 0; js < 4; js++) {
                short8 bk = *(const short8*)((const char*)sK + (js*16 + ln)*144 + kk*64 + g4*16);
                sacc[js] = __builtin_amdgcn_mfma_f32_16x16x32_bf16(aq, bk, sacc[js], 0, 0, 0);
            }
        }
        #pragma unroll
        for (int js = 0; js < 4; js++)
            #pragma unroll
            for (int r = 0; r < 4; r++) {
                float pv = bs2f((short)cur[js*4 + r]);
                float e = exp2f((sacc[js][r]*0.125f + pv)*LOG2E);
                lsum[r] += e;
                sP[w][(g4*4 + r)*72 + js*16 + ln] = f2bs(e);
            }
        #pragma unroll
        for (int kk = 0; kk < 2; kk++) {
            short8 ap = *(const short8*)((const char*)sP[w] + ln*144 + kk*64 + g4*16);
            #pragma unroll
            for (int ds = 0; ds < 4; ds++) {
                short8 bv = *(const short8*)((const char*)sV + (ds*16 + ln)*144 + kk*64 + g4*16);
                oacc[ds] = __builtin_amdgcn_mfma_f32_16x16x32_bf16(ap, bv, oacc[ds], 0, 0, 0);
            }
        }
    }

    #pragma unroll
    for (int r = 0; r < 4; r++)
        #pragma unroll
        for (int m = 1; m < 16; m <<= 1) lsum[r] += __shfl_xor(lsum[r], m, 64);

    #pragma unroll
    for (int ds = 0; ds < 4; ds++)
        #pragma unroll
        for (int r = 0; r < 4; r++) {
            float val = oacc[ds][r] / lsum[r];
            int gi = i0 + w*16 + g4*4 + r;
            int col = h*64 + ds*16 + ln;
            heads[((long)b*SEQL + gi)*PROJ + col] = __float2bfloat16(val);
        }
}

// ---------------- K4: fused tail: o-proj + LN + FFN + LN ----------------
// 256 blocks x 256 thr (4 waves); 8 rows/block, 2 rows/wave; vector LDS reads.
__global__ __launch_bounds__(256) void tail_kernel(
    const bf16* __restrict__ heads, const float* __restrict__ Wo,
    const float* __restrict__ seq, const float* __restrict__ g_att,
    const float* __restrict__ b_att, const float* __restrict__ W1,
    const float* __restrict__ b1, const float* __restrict__ W2,
    const float* __restrict__ b2, const float* __restrict__ g_ff,
    const float* __restrict__ b_ff, float* __restrict__ out)
{
    __shared__ __align__(16) short sH[8][520];
    __shared__ float sX[8][68];
    __shared__ float sHid[8][132];
    int t = threadIdx.x;
    int w = t >> 6, lane = t & 63;
    long g0 = (long)blockIdx.x*8;

    for (int idx = t; idx < 512; idx += 256) {
        int r = idx >> 6, c8 = idx & 63;
        *(uint4*)((char*)&sH[r][0] + c8*16) = *(const uint4*)(heads + (g0 + r)*PROJ + c8*8);
    }
    __syncthreads();

    int r0 = w*2, r1 = w*2 + 1;
    float acc0 = 0.f, acc1 = 0.f;
    #pragma unroll 4
    for (int kk8 = 0; kk8 < 64; kk8++) {
        short8 a0 = *(const short8*)&sH[r0][kk8*8];
        short8 a1 = *(const short8*)&sH[r1][kk8*8];
        #pragma unroll
        for (int e = 0; e < 8; e++) {
            float wv = Wo[(kk8*8 + e)*DEPTH + lane];
            acc0 += bs2f(a0[e])*wv;
            acc1 += bs2f(a1[e])*wv;
        }
    }
    float ga = g_att[lane], ba = b_att[lane];
    float xn[2];
    #pragma unroll
    for (int rr = 0; rr < 2; rr++) {
        long row = g0 + w*2 + rr;
        float x0 = (rr ? acc1 : acc0) + seq[row*DEPTH + lane];
        float s1 = x0, s2 = x0*x0;
        #pragma unroll
        for (int m = 1; m < 64; m <<= 1) { s1 += __shfl_xor(s1, m, 64); s2 += __shfl_xor(s2, m, 64); }
        float mu = s1*(1.f/64.f);
        float var = s2*(1.f/64.f) - mu*mu;
        float rstd = rsqrtf(var + 1e-5f);
        xn[rr] = (x0 - mu)*rstd*ga + ba;
        sX[w*2 + rr][lane] = xn[rr];
    }

    float b1a = b1[lane], b1b = b1[lane + 64];
    float h00 = b1a, h01 = b1b, h10 = b1a, h11 = b1b;
    #pragma unroll 4
    for (int kk = 0; kk < DEPTH; kk++) {
        float w0 = W1[kk*FFDIM + lane];
        float w1 = W1[kk*FFDIM + 64 + lane];
        float x0v = sX[r0][kk], x1v = sX[r1][kk];
        h00 += x0v*w0; h01 += x0v*w1;
        h10 += x1v*w0; h11 += x1v*w1;
    }
    sHid[r0][lane] = fmaxf(h00, 0.f); sHid[r0][lane + 64] = fmaxf(h01, 0.f);
    sHid[r1][lane] = fmaxf(h10, 0.f); sHid[r1][lane + 64] = fmaxf(h11, 0.f);

    float bb = b2[lane];
    float acc20 = bb, acc21 = bb;
    #pragma unroll 4
    for (int kk = 0; kk < FFDIM; kk++) {
        float wv = W2[kk*DEPTH + lane];
        acc20 += sHid[r0][kk]*wv;
        acc21 += sHid[r1][kk]*wv;
    }
    float gf = g_ff[lane], bf = b_ff[lane];
    #pragma unroll
    for (int rr = 0; rr < 2; rr++) {
        long row = g0 + w*2 + rr;
        float z = xn[rr] + (rr ? acc21 : acc20);
        float t1 = z, t2 = z*z;
        #pragma unroll
        for (int m = 1; m < 64; m <<= 1) { t1 += __shfl_xor(t1, m, 64); t2 += __shfl_xor(t2, m, 64); }
        float mu2 = t1*(1.f/64.f);
        float var2 = t2*(1.f/64.f) - mu2*mu2;
        float rstd2 = rsqrtf(var2 + 1e-5f);
        out[row*DEPTH + lane] = (z - mu2)*rstd2*gf + bf;
    }
}

extern "C" void kernel_launch(void* const* d_in, const int* in_sizes, int n_in,
                              void* d_out, int out_size, void* d_ws, size_t ws_size,
                              hipStream_t stream) {
    const float* seq   = (const float*)d_in[0];
    const float* pos   = (const float*)d_in[1];
    const float* Wq    = (const float*)d_in[2];
    const float* Wk    = (const float*)d_in[3];
    const float* Wv    = (const float*)d_in[4];
    const float* Wo    = (const float*)d_in[5];
    const float* Wp    = (const float*)d_in[6];
    const float* bp    = (const float*)d_in[7];
    const float* W1    = (const float*)d_in[8];
    const float* b1    = (const float*)d_in[9];
    const float* W2    = (const float*)d_in[10];
    const float* b2    = (const float*)d_in[11];
    const float* g_att = (const float*)d_in[12];
    const float* b_att = (const float*)d_in[13];
    const float* g_ff  = (const float*)d_in[14];
    const float* b_ff  = (const float*)d_in[15];
    float* outp = (float*)d_out;

    bf16* qb  = (bf16*)d_ws;
    bf16* kb  = qb + 1048576;
    bf16* vTb = kb + 1048576;      // [B,h,d,S]
    bf16* pb  = vTb + 1048576;     // [B,S,S,h]
    bf16* hb  = pb + 8388608;

    qkv_kernel  <<<dim3(32, 4, 3), 256, 0, stream>>>(seq, Wq, Wk, Wv, qb, kb, vTb);
    pbias_kernel<<<8192,           256, 0, stream>>>(pos, Wp, bp, pb);
    attn_kernel <<<256,            256, 0, stream>>>(qb, kb, vTb, pb, hb);
    tail_kernel <<<256,            256, 0, stream>>>(hb, Wo, seq, g_att, b_att,
                                                     W1, b1, W2, b2, g_ff, b_ff, outp);
}